// Round 13
// baseline (229.849 us; speedup 1.0000x reference)
//
#include <hip/hip_runtime.h>
#include <cstdint>

#define HH 512
#define WW 512
#define TX 58          // output tile width; 9 tiles cover 512 (last partial)
// grid = 16 * 64 * 9 = 9216 blocks

typedef __attribute__((ext_vector_type(8)))  short    short8;
typedef __attribute__((ext_vector_type(16))) float    f32x16;
typedef __attribute__((ext_vector_type(4)))  float    f32x4;
typedef __attribute__((ext_vector_type(2)))  unsigned u32x2;
typedef __attribute__((ext_vector_type(8)))  int      int8v;

union FragU { uint4 u; short8 s; };
union B8U   { u32x2 u2[2]; short8 s; };
union AF8   { uint4 u[2]; int8v v; };
union BF8   { unsigned d[8]; int8v v; };

// ---- LDS layout (bytes); fp8 act slot = 12B; row stride 832B (208dw==16 mod 32,
// conflict-minimal per R12) ----
#define L1F_O  0        // 14 rows x 832B (64 px = 768B used, tail zeroed)
#define L1W_O  11648
#define L1RST  832
#define MOS_O  23296    // 16 rows x 66 px x 8B bf16 (dead after L1) — aliases L2
#define MOSR   528
#define L2F_O  23296    // 12 rows x 832B (62 px = 744B used, tail zeroed)
#define L2W_O  33280
#define L2RST  832
#define RELAY_O 0       // aliases dead L1 during L3; 4 waves x 64 slots x 52B = 13312
#define GLDS_O 13312    // green plane 10 rows x 60 px x 4B (bf16 pair), aliases dead L1
#define SMEMB  43264    // 3 blocks/CU

#define MFMA_SC(A, B, C) \
  __builtin_amdgcn_mfma_scale_f32_16x16x128_f8f6f4((A), (B), (C), 0, 0, 0, 0x7F7F7F7Fu, 0, 0x7F7F7F7Fu)

__device__ __forceinline__ unsigned cvtpk(float a, float b) {
  unsigned r;
  asm("v_cvt_pk_bf16_f32 %0, %1, %2" : "=v"(r) : "v"(a), "v"(b));
  return r;
}
__device__ __forceinline__ unsigned rpk8(float a, float b, float c, float d, bool im) {
  int r = __builtin_amdgcn_cvt_pk_fp8_f32(fmaxf(a, 0.f), fmaxf(b, 0.f), 0, false);
  r = __builtin_amdgcn_cvt_pk_fp8_f32(fmaxf(c, 0.f), fmaxf(d, 0.f), r, true);
  return im ? (unsigned)r : 0u;
}
__device__ __forceinline__ unsigned short f2bf(float f) {
  union { float f; unsigned u; } v; v.f = f;
  unsigned r = v.u + 0x7fffu + ((v.u >> 16) & 1u);
  return (unsigned short)(r >> 16);
}
__device__ __forceinline__ float lo16(unsigned u) {
  union { unsigned v; float f; } x; x.v = u << 16; return x.f;
}
__device__ __forceinline__ float hi16(unsigned u) {
  union { unsigned v; float f; } x; x.v = u & 0xffff0000u; return x.f;
}

// ---------------- weight packer (EXACT R10/R12 mapping — HW-verified) ----------------
__global__ void wt_kernel(const float* __restrict__ fw0, const float* __restrict__ fw1,
                          const float* __restrict__ fw2, const float* __restrict__ ww0,
                          const float* __restrict__ ww1, const float* __restrict__ ww2,
                          uint4* __restrict__ wsf) {
  int t = blockIdx.x * 256 + threadIdx.x;
  if (t >= 448) return;
  if (t < 192) {
    int f = t >> 6, lane = t & 63;
    int h = (lane >> 5) & 1, m = lane & 31;
    unsigned short v[8];
#pragma unroll
    for (int e = 0; e < 8; ++e) {
      int sq = 2 * h + (e >> 2);
      int c4 = e & 3;
      float w = 0.f;
      if (sq < 3 && m < 24) {
        w = (m < 12) ? fw0[(m * 4 + c4) * 9 + f * 3 + sq]
                     : ww0[((m - 12) * 4 + c4) * 9 + f * 3 + sq];
      }
      v[e] = f2bf(w);
    }
    uint4 o;
    o.x = (unsigned)v[0] | ((unsigned)v[1] << 16);
    o.y = (unsigned)v[2] | ((unsigned)v[3] << 16);
    o.z = (unsigned)v[4] | ((unsigned)v[5] << 16);
    o.w = (unsigned)v[6] | ((unsigned)v[7] << 16);
    wsf[t] = o;
  } else {
    int u = t - 192, sid = u >> 6, lane = u & 63;
    int m = lane & 15, kg = lane >> 4;
    int layer = sid >> 1, path = sid & 1;
    const float* src = layer ? (path ? ww2 : fw2) : (path ? ww1 : fw1);
    const float scale = (layer == 1 && path == 1) ? 1.44269504f : 1.0f;
    unsigned d[8];
#pragma unroll
    for (int k = 0; k < 8; ++k) {
      float w4[4];
#pragma unroll
      for (int j4 = 0; j4 < 4; ++j4) {
        int e = 4 * k + j4;
        float w = 0.f;
        if (m < 12) {
          if (kg < 3) {
            int dx = e / 12, ci = e % 12, tap = kg * 3 + dx;
            w = src[(m * 12 + ci) * 9 + tap] * scale;
          } else {
            int i = e >> 3, j = e & 7;
            if (i < 3 && j < 4) {
              int tap = i * 3 + 2, ci = 8 + j;
              w = src[(m * 12 + ci) * 9 + tap] * scale;
            }
          }
        }
        w4[j4] = w;
      }
      int x = __builtin_amdgcn_cvt_pk_fp8_f32(w4[0], w4[1], 0, false);
      x = __builtin_amdgcn_cvt_pk_fp8_f32(w4[2], w4[3], x, true);
      d[k] = (unsigned)x;
    }
    uint4* dst = wsf + 192 + sid * 128 + lane * 2;
    dst[0] = make_uint4(d[0], d[1], d[2], d[3]);
    dst[1] = make_uint4(d[4], d[5], d[6], d[7]);
  }
}

// ------- fully fused: 3-layer x 2-path conv (MX K=128) + softmax green + chroma + shuffle -------
__global__ __launch_bounds__(256, 3)
void green_kernel(const float* __restrict__ mosaic, const uint4* __restrict__ wsf,
                  const float* __restrict__ cw0, float* __restrict__ out) {
  __shared__ __align__(16) char s[SMEMB];
  const int tid = threadIdx.x;
  const int lane = tid & 63;
  const int wv = __builtin_amdgcn_readfirstlane(tid >> 6);
  const int h = (lane >> 5) & 1, ln = lane & 31;
  const int ln8 = ln * 8, ln12 = ln * 12;
  const int pxl = lane & 15, kg = lane >> 4;
  const int bid = blockIdx.x;
  const int bx = bid % 9;
  const int t9 = bid / 9;
  const int by = t9 & 63, b = t9 >> 6;
  const int X0 = bx * TX, Y0 = by * 8;
  const float* __restrict__ mb = mosaic + (size_t)b * 4 * HH * WW;

  // ---- stage 0: mosaic tile 16x66 bf16 + zero L1 row tails ----
  {
    for (int p = tid; p < 16 * 66; p += 256) {
      int row = p / 66, col = p - row * 66;
      int gy = Y0 + row - 4, gx = X0 + col - 4;
      float c0 = 0.f, c1 = 0.f, c2 = 0.f, c3 = 0.f;
      if ((unsigned)gy < HH && (unsigned)gx < WW) {
        const float* mp = mb + (size_t)gy * WW + gx;
        c0 = mp[0]; c1 = mp[HH * WW]; c2 = mp[2 * HH * WW]; c3 = mp[3 * HH * WW];
      }
      u32x2 w = { cvtpk(c0, c1), cvtpk(c2, c3) };
      *(u32x2*)(s + MOS_O + row * MOSR + col * 8) = w;
    }
    for (int i = tid; i < 448; i += 256) {  // 28 segs x 16 dw: L1F/L1W tails 768..832
      int seg = i >> 4, d = i & 15;
      int row = seg % 14, w = seg / 14;
      *(unsigned*)(s + w * 11648 + row * 832 + 768 + d * 4) = 0u;
    }
  }
  __syncthreads();

  // ---- L1: 4->12 both paths (bf16 MFMA, M: F 0-11, W 12-23), out 14x64 fp8 ----
  {
    FragU a3[3];
#pragma unroll
    for (int q = 0; q < 3; ++q) a3[q].u = wsf[q * 64 + lane];
    const char* pLo = s + MOS_O + 4 * wv * MOSR + ln8 + 16 * h;
    const char* pHi = s + MOS_O + 4 * wv * MOSR + ln8 + 8;
    char* base = s + 4 * wv * L1RST + ln12;
    char* pA = base + L1F_O + 4 * h;
    char* pB = h ? base + L1W_O : base + L1F_O + 8;
    char* pC = base + L1W_O + (h ? 8 : 4);
    bool ck[2];
    ck[0] = (unsigned)(X0 + 0  + ln - 3) < WW;
    ck[1] = (unsigned)(X0 + 32 + ln - 3) < WW;
#pragma unroll
    for (int r = 0; r < 4; ++r) {
      const int ly = 4 * wv + r;
      if (ly < 14) {
        const bool rowok = (unsigned)(Y0 + ly - 3) < HH;
#pragma unroll
        for (int g = 0; g < 2; ++g) {
          const int cb = g * 32;
          f32x16 c = {};
#pragma unroll
          for (int ky = 0; ky < 3; ++ky) {
            B8U bu;
            bu.u2[0] = *(const u32x2*)(pLo + (r + ky) * MOSR + cb * 8);
            bu.u2[1] = *(const u32x2*)(pHi + (r + ky) * MOSR + cb * 8);
            c = __builtin_amdgcn_mfma_f32_32x32x16_bf16(a3[ky].s, bu.s, c, 0, 0, 0);
          }
          const bool im = rowok && ck[g];
          *(unsigned*)(pA + r * L1RST + cb * 12) = rpk8(c[0], c[1], c[2], c[3], im);
          *(unsigned*)(pB + r * L1RST + cb * 12) = rpk8(c[4], c[5], c[6], c[7], im);
          *(unsigned*)(pC + r * L1RST + cb * 12) = rpk8(c[8], c[9], c[10], c[11], im);
        }
      }
    }
  }
  __syncthreads();

  // ---- L2: 12->12 both chains, one scaled MFMA per 16px per chain, out 12x62 ----
  {
    for (int i = tid; i < 528; i += 256) {  // 24 segs x 22 dw: L2F/L2W tails 744..832
      int seg = i / 22, d = i - seg * 22;
      int row = seg % 12, w = seg / 12;
      *(unsigned*)(s + L2F_O + w * 9984 + row * 832 + 744 + d * 4) = 0u;
    }
    AF8 aF, aW;
    aF.u[0] = wsf[192 + lane * 2]; aF.u[1] = wsf[193 + lane * 2];
    aW.u[0] = wsf[320 + lane * 2]; aW.u[1] = wsf[321 + lane * 2];
    const int c0 = (wv == 0) ? 0 : (wv == 1) ? 16 : (wv == 2) ? 32 : 46;
    int o0, o1, o2, o3;
    if (kg < 3) { o0 = kg * L1RST + pxl * 12; o1 = o0 + 8; o2 = o0 + 16; o3 = o0 + 24; }
    else        { o0 = (pxl + 2) * 12 + 8; o1 = o0 + L1RST; o2 = o1 + L1RST; o3 = o2; }
    const char* P0 = s + L1F_O + c0 * 12 + o0;
    const char* P1 = s + L1F_O + c0 * 12 + o1;
    const char* P2 = s + L1F_O + c0 * 12 + o2;
    const char* P3 = s + L1F_O + c0 * 12 + o3;
    const bool ckx = (unsigned)(X0 + c0 + pxl - 2) < WW;
    char* pO = s + L2F_O + (c0 + pxl) * 12 + 4 * kg;
#pragma unroll
    for (int ly = 0; ly < 12; ++ly) {
      const int imm = ly * L1RST;
      BF8 bF, bW;
      bF.d[0] = *(const unsigned*)(P0 + imm);         bF.d[1] = *(const unsigned*)(P0 + imm + 4);
      bF.d[2] = *(const unsigned*)(P1 + imm);         bF.d[3] = *(const unsigned*)(P1 + imm + 4);
      bF.d[4] = *(const unsigned*)(P2 + imm);         bF.d[5] = *(const unsigned*)(P2 + imm + 4);
      bF.d[6] = *(const unsigned*)(P3 + imm);         bF.d[7] = *(const unsigned*)(P3 + imm + 4);
      bW.d[0] = *(const unsigned*)(P0 + imm + 11648); bW.d[1] = *(const unsigned*)(P0 + imm + 11652);
      bW.d[2] = *(const unsigned*)(P1 + imm + 11648); bW.d[3] = *(const unsigned*)(P1 + imm + 11652);
      bW.d[4] = *(const unsigned*)(P2 + imm + 11648); bW.d[5] = *(const unsigned*)(P2 + imm + 11652);
      bW.d[6] = *(const unsigned*)(P3 + imm + 11648); bW.d[7] = *(const unsigned*)(P3 + imm + 11652);
      f32x4 cF = {0.f, 0.f, 0.f, 0.f}, cW = {0.f, 0.f, 0.f, 0.f};
      cF = MFMA_SC(aF.v, bF.v, cF);
      cW = MFMA_SC(aW.v, bW.v, cW);
      const bool im = ckx && ((unsigned)(Y0 + ly - 2) < HH);
      if (kg < 3) {
        *(unsigned*)(pO + ly * L2RST)        = rpk8(cF[0], cF[1], cF[2], cF[3], im);
        *(unsigned*)(pO + ly * L2RST + 9984) = rpk8(cW[0], cW[1], cW[2], cW[3], im);
      }
    }
  }
  __syncthreads();

  // ---- L3: scaled MFMA + relay softmax -> green LDS plane 10x60 ----
  {
    AF8 aF, aW;
    aF.u[0] = wsf[448 + lane * 2]; aF.u[1] = wsf[449 + lane * 2];
    aW.u[0] = wsf[576 + lane * 2]; aW.u[1] = wsf[577 + lane * 2];
    const int c0 = (wv == 0) ? 0 : (wv == 1) ? 16 : (wv == 2) ? 32 : 44;
    int o0, o1, o2, o3;
    if (kg < 3) { o0 = kg * L2RST + pxl * 12; o1 = o0 + 8; o2 = o0 + 16; o3 = o0 + 24; }
    else        { o0 = (pxl + 2) * 12 + 8; o1 = o0 + L2RST; o2 = o1 + L2RST; o3 = o2; }
    const char* P0 = s + L2F_O + c0 * 12 + o0;
    const char* P1 = s + L2F_O + c0 * 12 + o1;
    const char* P2 = s + L2F_O + c0 * 12 + o2;
    const char* P3 = s + L2F_O + c0 * 12 + o3;
    char* relay = s + RELAY_O + wv * 3328;
#pragma unroll
    for (int r2 = 0; r2 < 3; ++r2) {
#pragma unroll
      for (int rr = 0; rr < 4; ++rr) {
        const int ly = r2 * 4 + rr;
        if (ly < 10) {
          const int imm = ly * L2RST;
          BF8 bF, bW;
          bF.d[0] = *(const unsigned*)(P0 + imm);        bF.d[1] = *(const unsigned*)(P0 + imm + 4);
          bF.d[2] = *(const unsigned*)(P1 + imm);        bF.d[3] = *(const unsigned*)(P1 + imm + 4);
          bF.d[4] = *(const unsigned*)(P2 + imm);        bF.d[5] = *(const unsigned*)(P2 + imm + 4);
          bF.d[6] = *(const unsigned*)(P3 + imm);        bF.d[7] = *(const unsigned*)(P3 + imm + 4);
          bW.d[0] = *(const unsigned*)(P0 + imm + 9984); bW.d[1] = *(const unsigned*)(P0 + imm + 9988);
          bW.d[2] = *(const unsigned*)(P1 + imm + 9984); bW.d[3] = *(const unsigned*)(P1 + imm + 9988);
          bW.d[4] = *(const unsigned*)(P2 + imm + 9984); bW.d[5] = *(const unsigned*)(P2 + imm + 9988);
          bW.d[6] = *(const unsigned*)(P3 + imm + 9984); bW.d[7] = *(const unsigned*)(P3 + imm + 9988);
          f32x4 cF = {0.f, 0.f, 0.f, 0.f}, cW = {0.f, 0.f, 0.f, 0.f};
          cF = MFMA_SC(aF.v, bF.v, cF);
          cW = MFMA_SC(aW.v, bW.v, cW);
          if (kg < 3) {
            char* slot = relay + ((rr << 4) + pxl) * 52 + kg * 8;
            *(unsigned*)(slot)      = cvtpk(fmaxf(cF[0], 0.f), fmaxf(cF[1], 0.f));
            *(unsigned*)(slot + 4)  = cvtpk(fmaxf(cF[2], 0.f), fmaxf(cF[3], 0.f));
            *(unsigned*)(slot + 24) = cvtpk(fmaxf(cW[0], 0.f), fmaxf(cW[1], 0.f));
            *(unsigned*)(slot + 28) = cvtpk(fmaxf(cW[2], 0.f), fmaxf(cW[3], 0.f));
          }
        }
      }
      asm volatile("s_waitcnt lgkmcnt(0)" ::: "memory");
      {
        const int row = r2 * 4 + kg;
        if (row < 10) {
          const char* slot = relay + lane * 52;
          unsigned fu[6], wu[6];
#pragma unroll
          for (int i = 0; i < 6; ++i) {
            fu[i] = *(const unsigned*)(slot + i * 4);
            wu[i] = *(const unsigned*)(slot + 24 + i * 4);
          }
          float F[12], Wv[12];
#pragma unroll
          for (int i = 0; i < 6; ++i) {
            F[2 * i] = lo16(fu[i]);  F[2 * i + 1] = hi16(fu[i]);
            Wv[2 * i] = lo16(wu[i]); Wv[2 * i + 1] = hi16(wu[i]);
          }
          float m = 0.f;
#pragma unroll
          for (int c2 = 0; c2 < 12; ++c2) m = fmaxf(m, Wv[c2]);
          float sum = 0.f, s0 = 0.f, s1 = 0.f;
#pragma unroll
          for (int c2 = 0; c2 < 12; ++c2) {
            const float e = exp2f(Wv[c2] - m);   // W logits pre-scaled by 1/ln2
            sum += e;
            if (c2 < 6) s0 = fmaf(F[c2], e, s0);
            else        s1 = fmaf(F[c2], e, s1);
          }
          const float inv = 1.f / sum;
          *(unsigned*)(s + GLDS_O + (row * 60 + c0 + pxl) * 4) = cvtpk(s0 * inv, s1 * inv);
        }
      }
      asm volatile("s_waitcnt lgkmcnt(0)" ::: "memory");
    }
  }
  __syncthreads();

  // ---- assemble: chroma conv 2->6 + green_add + pixel-shuffle, out 8x58 RGB ----
  for (int i = tid; i < 8 * TX; i += 256) {
    const int orow = i / TX, ocol = i - orow * TX;
    const int gy = Y0 + orow, gx = X0 + ocol;
    const int p = gy * WW + gx;
    const unsigned gpk = *(const unsigned*)(s + GLDS_O + ((orow + 1) * 60 + ocol + 1) * 4);
    const float g0 = lo16(gpk), g1 = hi16(gpk);
    float cd[6] = {0.f, 0.f, 0.f, 0.f, 0.f, 0.f};
#pragma unroll
    for (int ky = 0; ky < 3; ++ky) {
#pragma unroll
      for (int kx = 0; kx < 3; ++kx) {
        const int yy = gy + ky - 1, xx = gx + kx - 1;
        float c0 = 0.f, c1 = 0.f;
        if ((unsigned)yy < HH && (unsigned)xx < WW) {
          const int q = yy * WW + xx;
          const unsigned gg = *(const unsigned*)(s + GLDS_O + ((orow + ky) * 60 + ocol + kx) * 4);
          c0 = mb[HH * WW + q]     - lo16(gg);
          c1 = mb[2 * HH * WW + q] - hi16(gg);
        }
        const int k = ky * 3 + kx;
#pragma unroll
        for (int o = 0; o < 6; ++o) {
          cd[o] = fmaf(c0, cw0[(o * 2 + 0) * 9 + k], cd[o]);
          cd[o] = fmaf(c1, cw0[(o * 2 + 1) * 9 + k], cd[o]);
        }
      }
    }
    if (gx < WW) {
      const float m0 = mb[p];
      const float m1 = mb[HH * WW + p];
      const float m2 = mb[2 * HH * WW + p];
      const float m3 = mb[3 * HH * WW + p];
      const float cp0 = cd[0] + m0;
      const float cp1 = cd[1] + g1;
      const float cp2 = cd[2] + m3;
      const float cp3 = cd[3] + m0;
      const float cp4 = cd[4] + g0;
      const float cp5 = cd[5] + m3;
      const int W2 = 2 * WW;
      const size_t plane = (size_t)(2 * HH) * W2;
      size_t base = ((size_t)(b * 3) * (2 * HH) + 2 * gy) * W2 + 2 * gx;
      *(float2*)(out + base)              = make_float2(cp0, m1);
      *(float2*)(out + base + W2)         = make_float2(cp1, cp2);
      *(float2*)(out + base + plane)      = make_float2(m0, g0);
      *(float2*)(out + base + plane + W2) = make_float2(g1, m3);
      *(float2*)(out + base + 2 * plane)      = make_float2(cp3, cp4);
      *(float2*)(out + base + 2 * plane + W2) = make_float2(m2, cp5);
    }
  }
}

extern "C" void kernel_launch(void* const* d_in, const int* in_sizes, int n_in,
                              void* d_out, int out_size, void* d_ws, size_t ws_size,
                              hipStream_t stream) {
  const float* mosaic = (const float*)d_in[0];
  const float* fw0 = (const float*)d_in[1];
  const float* fw1 = (const float*)d_in[2];
  const float* fw2 = (const float*)d_in[3];
  const float* ww0 = (const float*)d_in[4];
  const float* ww1 = (const float*)d_in[5];
  const float* ww2 = (const float*)d_in[6];
  const float* cw0 = (const float*)d_in[7];

  uint4* wsf = (uint4*)((char*)d_ws + 32768);
  float* out = (float*)d_out;

  wt_kernel<<<2, 256, 0, stream>>>(fw0, fw1, fw2, ww0, ww1, ww2, wsf);
  green_kernel<<<16 * 64 * 9, 256, 0, stream>>>(mosaic, wsf, cw0, out);
}

// Round 14
// 192.460 us; speedup vs baseline: 1.1943x; 1.1943x over previous
//
#include <hip/hip_runtime.h>
#include <cstdint>

#define HH 512
#define WW 512
#define TX 58          // output tile width; 9 tiles cover 512 (last partial)
// grid = 16 * 64 * 9 = 9216 blocks

typedef __attribute__((ext_vector_type(8)))  short    short8;
typedef __attribute__((ext_vector_type(16))) float    f32x16;
typedef __attribute__((ext_vector_type(4)))  float    f32x4;
typedef __attribute__((ext_vector_type(2)))  unsigned u32x2;
typedef __attribute__((ext_vector_type(8)))  int      int8v;

union FragU { uint4 u; short8 s; };
union B8U   { u32x2 u2[2]; short8 s; };
union AF8   { uint4 u[2]; int8v v; };
union BF8   { unsigned d[8]; int8v v; };

// ---- LDS layout (bytes); fp8 act slot = 12B; row stride 832B (208dw==16 mod 32,
// conflict-minimal per R12) ----
#define L1F_O  0        // 12 rows x 832B (62 px = 744B used, tail zeroed)
#define L1W_O  9984
#define L1RST  832
#define MOS_O  19968    // 14 rows x 64 px x 8B bf16 (dead after L1)
#define MOSR   512
#define L2F_O  19968    // aliases mosaic; 10 rows x 832B (60 px = 720B used, tail zeroed)
#define L2W_O  28288
#define L2RST  832
#define RELAY_O 0       // aliases dead L1 during L3; 4 waves x 64 slots x 52B = 13312
#define SMEMB  36608    // 4 blocks/CU

#define MFMA_SC(A, B, C) \
  __builtin_amdgcn_mfma_scale_f32_16x16x128_f8f6f4((A), (B), (C), 0, 0, 0, 0x7F7F7F7Fu, 0, 0x7F7F7F7Fu)

__device__ __forceinline__ unsigned cvtpk(float a, float b) {
  unsigned r;
  asm("v_cvt_pk_bf16_f32 %0, %1, %2" : "=v"(r) : "v"(a), "v"(b));
  return r;
}
__device__ __forceinline__ unsigned rpk8(float a, float b, float c, float d, bool im) {
  int r = __builtin_amdgcn_cvt_pk_fp8_f32(fmaxf(a, 0.f), fmaxf(b, 0.f), 0, false);
  r = __builtin_amdgcn_cvt_pk_fp8_f32(fmaxf(c, 0.f), fmaxf(d, 0.f), r, true);
  return im ? (unsigned)r : 0u;
}
__device__ __forceinline__ unsigned short f2bf(float f) {
  union { float f; unsigned u; } v; v.f = f;
  unsigned r = v.u + 0x7fffu + ((v.u >> 16) & 1u);
  return (unsigned short)(r >> 16);
}
__device__ __forceinline__ float bf2f(unsigned short b) {
  union { unsigned u; float f; } v; v.u = ((unsigned)b) << 16;
  return v.f;
}
__device__ __forceinline__ float lo16(unsigned u) {
  union { unsigned v; float f; } x; x.v = u << 16; return x.f;
}
__device__ __forceinline__ float hi16(unsigned u) {
  union { unsigned v; float f; } x; x.v = u & 0xffff0000u; return x.f;
}

// ---------------- weight packer (EXACT R10/R12 mapping — HW-verified) ----------------
// t 0-191: L1 merged bf16 frags (f=t>>6=ky), rows 0-11 fw0, 12-23 ww0;
//          slot sq = 2h + e/4 -> kx = sq (sq==3 zero). 16B/lane.
// t 192-447: scaled K=128 frags, sid={L2F,L2W,L3F,L3W} at 192+sid*128+lane*2.
//   lane: m=lane&15 (co), kg=lane>>4.
//   kg<3 : byte e (0-31): dx=e/12, ci=e%12, tap=kg*3+dx.
//   kg==3: e=8i+j, valid i<3,j<4: tap=i*3+2, ci=8+j (row-tails); else 0.
// L3 W set pre-scaled 1/ln2 (softmax via exp2).
__global__ void wt_kernel(const float* __restrict__ fw0, const float* __restrict__ fw1,
                          const float* __restrict__ fw2, const float* __restrict__ ww0,
                          const float* __restrict__ ww1, const float* __restrict__ ww2,
                          uint4* __restrict__ wsf) {
  int t = blockIdx.x * 256 + threadIdx.x;
  if (t >= 448) return;
  if (t < 192) {
    int f = t >> 6, lane = t & 63;
    int h = (lane >> 5) & 1, m = lane & 31;
    unsigned short v[8];
#pragma unroll
    for (int e = 0; e < 8; ++e) {
      int sq = 2 * h + (e >> 2);
      int c4 = e & 3;
      float w = 0.f;
      if (sq < 3 && m < 24) {
        w = (m < 12) ? fw0[(m * 4 + c4) * 9 + f * 3 + sq]
                     : ww0[((m - 12) * 4 + c4) * 9 + f * 3 + sq];
      }
      v[e] = f2bf(w);
    }
    uint4 o;
    o.x = (unsigned)v[0] | ((unsigned)v[1] << 16);
    o.y = (unsigned)v[2] | ((unsigned)v[3] << 16);
    o.z = (unsigned)v[4] | ((unsigned)v[5] << 16);
    o.w = (unsigned)v[6] | ((unsigned)v[7] << 16);
    wsf[t] = o;
  } else {
    int u = t - 192, sid = u >> 6, lane = u & 63;
    int m = lane & 15, kg = lane >> 4;
    int layer = sid >> 1, path = sid & 1;
    const float* src = layer ? (path ? ww2 : fw2) : (path ? ww1 : fw1);
    const float scale = (layer == 1 && path == 1) ? 1.44269504f : 1.0f;
    unsigned d[8];
#pragma unroll
    for (int k = 0; k < 8; ++k) {
      float w4[4];
#pragma unroll
      for (int j4 = 0; j4 < 4; ++j4) {
        int e = 4 * k + j4;
        float w = 0.f;
        if (m < 12) {
          if (kg < 3) {
            int dx = e / 12, ci = e % 12, tap = kg * 3 + dx;
            w = src[(m * 12 + ci) * 9 + tap] * scale;
          } else {
            int i = e >> 3, j = e & 7;
            if (i < 3 && j < 4) {
              int tap = i * 3 + 2, ci = 8 + j;
              w = src[(m * 12 + ci) * 9 + tap] * scale;
            }
          }
        }
        w4[j4] = w;
      }
      int x = __builtin_amdgcn_cvt_pk_fp8_f32(w4[0], w4[1], 0, false);
      x = __builtin_amdgcn_cvt_pk_fp8_f32(w4[2], w4[3], x, true);
      d[k] = (unsigned)x;
    }
    uint4* dst = wsf + 192 + sid * 128 + lane * 2;
    dst[0] = make_uint4(d[0], d[1], d[2], d[3]);
    dst[1] = make_uint4(d[4], d[5], d[6], d[7]);
  }
}

// ---------------- fused 3-layer x 2-path conv (MX K=128 MFMA) + softmax green ----------------
// Also writes the G output plane (center-only, no halo needed) — removes 67MB from assemble.
__global__ __launch_bounds__(256, 4)
void green_kernel(const float* __restrict__ mosaic, const uint4* __restrict__ wsf,
                  unsigned short* __restrict__ green, float* __restrict__ out) {
  __shared__ __align__(16) char s[SMEMB];
  const int tid = threadIdx.x;
  const int lane = tid & 63;
  const int wv = __builtin_amdgcn_readfirstlane(tid >> 6);
  const int h = (lane >> 5) & 1, ln = lane & 31;
  const int ln8 = ln * 8, ln12 = ln * 12;
  const int pxl = lane & 15, kg = lane >> 4;
  const int bid = blockIdx.x;
  const int bx = bid % 9;
  const int t9 = bid / 9;
  const int by = t9 & 63, b = t9 >> 6;
  const int X0 = bx * TX, Y0 = by * 8;
  const float* __restrict__ mb = mosaic + (size_t)b * 4 * HH * WW;

  // ---- stage 0: mosaic tile 14x64 bf16 + zero L1 row tails (pad-read safety) ----
  {
    for (int p = tid; p < 14 * 64; p += 256) {
      int row = p >> 6, col = p & 63;
      int gy = Y0 + row - 3, gx = X0 + col - 3;
      float c0 = 0.f, c1 = 0.f, c2 = 0.f, c3 = 0.f;
      if ((unsigned)gy < HH && (unsigned)gx < WW) {
        const float* mp = mb + (size_t)gy * WW + gx;
        c0 = mp[0]; c1 = mp[HH * WW]; c2 = mp[2 * HH * WW]; c3 = mp[3 * HH * WW];
      }
      u32x2 w = { cvtpk(c0, c1), cvtpk(c2, c3) };
      *(u32x2*)(s + MOS_O + row * MOSR + col * 8) = w;
    }
    for (int i = tid; i < 528; i += 256) {   // 24 segs x 22 dw: L1F/L1W tails 744..832
      int seg = i / 22, d = i - seg * 22;
      int row = seg % 12, w = seg / 12;
      *(unsigned*)(s + w * 9984 + row * 832 + 744 + d * 4) = 0u;
    }
  }
  __syncthreads();

  // ---- L1: 4->12 both paths in one bf16 MFMA (M: F 0-11, W 12-23), out 12x62 fp8 ----
  {
    FragU a3[3];
#pragma unroll
    for (int q = 0; q < 3; ++q) a3[q].u = wsf[q * 64 + lane];
    const char* pLo = s + MOS_O + 3 * wv * MOSR + ln8 + 16 * h;
    const char* pHi = s + MOS_O + 3 * wv * MOSR + ln8 + 8;
    char* base = s + 3 * wv * L1RST + ln12;
    char* pA = base + L1F_O + 4 * h;
    char* pB = h ? base + L1W_O : base + L1F_O + 8;
    char* pC = base + L1W_O + (h ? 8 : 4);
    bool ck[2];
    ck[0] = (unsigned)(X0 + 0  + ln - 2) < WW;
    ck[1] = (unsigned)(X0 + 30 + ln - 2) < WW;
#pragma unroll
    for (int r = 0; r < 3; ++r) {
      const int ly = 3 * wv + r;
      const bool rowok = (unsigned)(Y0 + ly - 2) < HH;
#pragma unroll
      for (int g = 0; g < 2; ++g) {
        const int cb = g * 30;
        f32x16 c = {};
#pragma unroll
        for (int ky = 0; ky < 3; ++ky) {
          B8U bu;
          bu.u2[0] = *(const u32x2*)(pLo + (r + ky) * MOSR + cb * 8);
          bu.u2[1] = *(const u32x2*)(pHi + (r + ky) * MOSR + cb * 8);
          c = __builtin_amdgcn_mfma_f32_32x32x16_bf16(a3[ky].s, bu.s, c, 0, 0, 0);
        }
        const bool im = rowok && ck[g];
        *(unsigned*)(pA + r * L1RST + cb * 12) = rpk8(c[0], c[1], c[2], c[3], im);
        *(unsigned*)(pB + r * L1RST + cb * 12) = rpk8(c[4], c[5], c[6], c[7], im);
        *(unsigned*)(pC + r * L1RST + cb * 12) = rpk8(c[8], c[9], c[10], c[11], im);
      }
    }
  }
  __syncthreads();

  // ---- L2: 12->12 both chains, ONE scaled MFMA per 16px per chain, out 10x60 ----
  {
    // zero L2F/L2W row tails 720..832 (mosaic now dead; visible to L3 via next barrier)
    for (int i = tid; i < 560; i += 256) {   // 20 segs x 28 dw
      int seg = i / 28, d = i - seg * 28;
      int row = seg % 10, w = seg / 10;
      *(unsigned*)(s + L2F_O + w * 8320 + row * 832 + 720 + d * 4) = 0u;
    }
    AF8 aF, aW;
    aF.u[0] = wsf[192 + lane * 2]; aF.u[1] = wsf[193 + lane * 2];
    aW.u[0] = wsf[320 + lane * 2]; aW.u[1] = wsf[321 + lane * 2];
    const int c0 = (wv == 0) ? 0 : (wv == 1) ? 16 : (wv == 2) ? 32 : 44;
    int o0, o1, o2, o3;
    if (kg < 3) { o0 = kg * L1RST + pxl * 12; o1 = o0 + 8; o2 = o0 + 16; o3 = o0 + 24; }
    else        { o0 = (pxl + 2) * 12 + 8; o1 = o0 + L1RST; o2 = o1 + L1RST; o3 = o2; }
    const char* P0 = s + L1F_O + c0 * 12 + o0;
    const char* P1 = s + L1F_O + c0 * 12 + o1;
    const char* P2 = s + L1F_O + c0 * 12 + o2;
    const char* P3 = s + L1F_O + c0 * 12 + o3;
    const bool ckx = (unsigned)(X0 + c0 + pxl - 1) < WW;
    char* pO = s + L2F_O + (c0 + pxl) * 12 + 4 * kg;
#pragma unroll
    for (int ly = 0; ly < 10; ++ly) {
      const int imm = ly * L1RST;
      BF8 bF, bW;
      bF.d[0] = *(const unsigned*)(P0 + imm);        bF.d[1] = *(const unsigned*)(P0 + imm + 4);
      bF.d[2] = *(const unsigned*)(P1 + imm);        bF.d[3] = *(const unsigned*)(P1 + imm + 4);
      bF.d[4] = *(const unsigned*)(P2 + imm);        bF.d[5] = *(const unsigned*)(P2 + imm + 4);
      bF.d[6] = *(const unsigned*)(P3 + imm);        bF.d[7] = *(const unsigned*)(P3 + imm + 4);
      bW.d[0] = *(const unsigned*)(P0 + imm + 9984); bW.d[1] = *(const unsigned*)(P0 + imm + 9988);
      bW.d[2] = *(const unsigned*)(P1 + imm + 9984); bW.d[3] = *(const unsigned*)(P1 + imm + 9988);
      bW.d[4] = *(const unsigned*)(P2 + imm + 9984); bW.d[5] = *(const unsigned*)(P2 + imm + 9988);
      bW.d[6] = *(const unsigned*)(P3 + imm + 9984); bW.d[7] = *(const unsigned*)(P3 + imm + 9988);
      f32x4 cF = {0.f, 0.f, 0.f, 0.f}, cW = {0.f, 0.f, 0.f, 0.f};
      cF = MFMA_SC(aF.v, bF.v, cF);
      cW = MFMA_SC(aW.v, bW.v, cW);
      const bool im = ckx && ((unsigned)(Y0 + ly - 1) < HH);
      if (kg < 3) {
        *(unsigned*)(pO + ly * L2RST)        = rpk8(cF[0], cF[1], cF[2], cF[3], im);
        *(unsigned*)(pO + ly * L2RST + 8320) = rpk8(cW[0], cW[1], cW[2], cW[3], im);
      }
    }
  }
  __syncthreads();

  // ---- L3: scaled MFMA + relay (52B slots) + softmax -> green + G-plane, out 8x58 ----
  {
    AF8 aF, aW;
    aF.u[0] = wsf[448 + lane * 2]; aF.u[1] = wsf[449 + lane * 2];
    aW.u[0] = wsf[576 + lane * 2]; aW.u[1] = wsf[577 + lane * 2];
    const int c0 = (wv == 0) ? 0 : (wv == 1) ? 16 : (wv == 2) ? 32 : 42;
    int o0, o1, o2, o3;
    if (kg < 3) { o0 = kg * L2RST + pxl * 12; o1 = o0 + 8; o2 = o0 + 16; o3 = o0 + 24; }
    else        { o0 = (pxl + 2) * 12 + 8; o1 = o0 + L2RST; o2 = o1 + L2RST; o3 = o2; }
    const char* P0 = s + L2F_O + c0 * 12 + o0;
    const char* P1 = s + L2F_O + c0 * 12 + o1;
    const char* P2 = s + L2F_O + c0 * 12 + o2;
    const char* P3 = s + L2F_O + c0 * 12 + o3;
    char* relay = s + RELAY_O + wv * 3328;
#pragma unroll
    for (int half = 0; half < 2; ++half) {
#pragma unroll
      for (int rr = 0; rr < 4; ++rr) {
        const int imm = (half * 4 + rr) * L2RST;
        BF8 bF, bW;
        bF.d[0] = *(const unsigned*)(P0 + imm);        bF.d[1] = *(const unsigned*)(P0 + imm + 4);
        bF.d[2] = *(const unsigned*)(P1 + imm);        bF.d[3] = *(const unsigned*)(P1 + imm + 4);
        bF.d[4] = *(const unsigned*)(P2 + imm);        bF.d[5] = *(const unsigned*)(P2 + imm + 4);
        bF.d[6] = *(const unsigned*)(P3 + imm);        bF.d[7] = *(const unsigned*)(P3 + imm + 4);
        bW.d[0] = *(const unsigned*)(P0 + imm + 8320); bW.d[1] = *(const unsigned*)(P0 + imm + 8324);
        bW.d[2] = *(const unsigned*)(P1 + imm + 8320); bW.d[3] = *(const unsigned*)(P1 + imm + 8324);
        bW.d[4] = *(const unsigned*)(P2 + imm + 8320); bW.d[5] = *(const unsigned*)(P2 + imm + 8324);
        bW.d[6] = *(const unsigned*)(P3 + imm + 8320); bW.d[7] = *(const unsigned*)(P3 + imm + 8324);
        f32x4 cF = {0.f, 0.f, 0.f, 0.f}, cW = {0.f, 0.f, 0.f, 0.f};
        cF = MFMA_SC(aF.v, bF.v, cF);
        cW = MFMA_SC(aW.v, bW.v, cW);
        if (kg < 3) {
          char* slot = relay + ((rr << 4) + pxl) * 52 + kg * 8;
          *(unsigned*)(slot)      = cvtpk(fmaxf(cF[0], 0.f), fmaxf(cF[1], 0.f));
          *(unsigned*)(slot + 4)  = cvtpk(fmaxf(cF[2], 0.f), fmaxf(cF[3], 0.f));
          *(unsigned*)(slot + 24) = cvtpk(fmaxf(cW[0], 0.f), fmaxf(cW[1], 0.f));
          *(unsigned*)(slot + 28) = cvtpk(fmaxf(cW[2], 0.f), fmaxf(cW[3], 0.f));
        }
      }
      asm volatile("s_waitcnt lgkmcnt(0)" ::: "memory");
      {
        const char* slot = relay + lane * 52;
        unsigned fu[6], wu[6];
#pragma unroll
        for (int i = 0; i < 6; ++i) {
          fu[i] = *(const unsigned*)(slot + i * 4);
          wu[i] = *(const unsigned*)(slot + 24 + i * 4);
        }
        float F[12], Wv[12];
#pragma unroll
        for (int i = 0; i < 6; ++i) {
          F[2 * i] = lo16(fu[i]);  F[2 * i + 1] = hi16(fu[i]);
          Wv[2 * i] = lo16(wu[i]); Wv[2 * i + 1] = hi16(wu[i]);
        }
        float m = 0.f;
#pragma unroll
        for (int c2 = 0; c2 < 12; ++c2) m = fmaxf(m, Wv[c2]);
        float sum = 0.f, s0 = 0.f, s1 = 0.f;
#pragma unroll
        for (int c2 = 0; c2 < 12; ++c2) {
          const float e = exp2f(Wv[c2] - m);   // W logits pre-scaled by 1/ln2
          sum += e;
          if (c2 < 6) s0 = fmaf(F[c2], e, s0);
          else        s1 = fmaf(F[c2], e, s1);
        }
        const float inv = 1.f / sum;
        const float g0s = s0 * inv, g1s = s1 * inv;
        const unsigned pg = cvtpk(g0s, g1s);
        const int gy = Y0 + half * 4 + kg;
        const int gx = X0 + c0 + pxl;
        if ((unsigned)gx < WW) {
          green[((b * 2 + 0) * HH + gy) * WW + gx] = (unsigned short)pg;
          green[((b * 2 + 1) * HH + gy) * WW + gx] = (unsigned short)(pg >> 16);
          // G output plane: tl=m0 tr=g0 / bl=g1 br=m3 (center-only, fp32 green)
          const int p = gy * WW + gx;
          const float m0 = mb[p];
          const float m3 = mb[3 * HH * WW + p];
          const int W2 = 2 * WW;
          size_t gbase = (((size_t)(b * 3 + 1)) * (2 * HH) + 2 * gy) * (size_t)W2 + 2 * gx;
          *(float2*)(out + gbase)      = make_float2(m0, g0s);
          *(float2*)(out + gbase + W2) = make_float2(g1s, m3);
        }
      }
      asm volatile("s_waitcnt lgkmcnt(0)" ::: "memory");
    }
  }
}

// ---------------- chroma conv 2->6 + pixel-shuffle assembly (R and B planes only) ----------------
__global__ __launch_bounds__(256)
void assemble_kernel(const float* __restrict__ mosaic, const unsigned short* __restrict__ green,
                     const float* __restrict__ cw0, float* __restrict__ out) {
  const int t = blockIdx.x * 256 + threadIdx.x;
  const int x = t & (WW - 1);
  const int y = (t >> 9) & (HH - 1);
  const int b = t >> 18;

  const int p = y * WW + x;
  const float* __restrict__ mb = mosaic + (size_t)b * 4 * HH * WW;
  const unsigned short* __restrict__ gb = green + (size_t)b * 2 * HH * WW;

  const float m0 = mb[p];
  const float m1 = mb[HH * WW + p];
  const float m2 = mb[2 * HH * WW + p];
  const float m3 = mb[3 * HH * WW + p];
  const float g0 = bf2f(gb[p]);
  const float g1 = bf2f(gb[HH * WW + p]);

  float cd[6] = {0.f, 0.f, 0.f, 0.f, 0.f, 0.f};
#pragma unroll
  for (int ky = 0; ky < 3; ++ky) {
#pragma unroll
    for (int kx = 0; kx < 3; ++kx) {
      const int yy = y + ky - 1, xx = x + kx - 1;
      float c0 = 0.f, c1 = 0.f;
      if ((unsigned)yy < HH && (unsigned)xx < WW) {
        const int q = yy * WW + xx;
        c0 = mb[HH * WW + q]     - bf2f(gb[q]);
        c1 = mb[2 * HH * WW + q] - bf2f(gb[HH * WW + q]);
      }
      const int k = ky * 3 + kx;
#pragma unroll
      for (int o = 0; o < 6; ++o) {
        cd[o] = fmaf(c0, cw0[(o * 2 + 0) * 9 + k], cd[o]);
        cd[o] = fmaf(c1, cw0[(o * 2 + 1) * 9 + k], cd[o]);
      }
    }
  }
  const float cp0 = cd[0] + m0;
  const float cp1 = cd[1] + g1;
  const float cp2 = cd[2] + m3;
  const float cp3 = cd[3] + m0;
  const float cp4 = cd[4] + g0;
  const float cp5 = cd[5] + m3;

  const int W2 = 2 * WW;
  const size_t plane = (size_t)(2 * HH) * W2;
  size_t base = ((size_t)(b * 3) * (2 * HH) + 2 * y) * W2 + 2 * x;
  // R: tl=cp0 tr=m1 / bl=cp1 br=cp2
  *(float2*)(out + base)          = make_float2(cp0, m1);
  *(float2*)(out + base + W2)     = make_float2(cp1, cp2);
  // (G plane written by green_kernel)
  // B: tl=cp3 tr=cp4 / bl=m2 br=cp5
  *(float2*)(out + base + 2 * plane)      = make_float2(cp3, cp4);
  *(float2*)(out + base + 2 * plane + W2) = make_float2(m2, cp5);
}

extern "C" void kernel_launch(void* const* d_in, const int* in_sizes, int n_in,
                              void* d_out, int out_size, void* d_ws, size_t ws_size,
                              hipStream_t stream) {
  const float* mosaic = (const float*)d_in[0];
  const float* fw0 = (const float*)d_in[1];
  const float* fw1 = (const float*)d_in[2];
  const float* fw2 = (const float*)d_in[3];
  const float* ww0 = (const float*)d_in[4];
  const float* ww1 = (const float*)d_in[5];
  const float* ww2 = (const float*)d_in[6];
  const float* cw0 = (const float*)d_in[7];

  uint4* wsf = (uint4*)((char*)d_ws + 32768);
  unsigned short* green = (unsigned short*)((char*)d_ws + 67584);
  float* out = (float*)d_out;

  wt_kernel<<<2, 256, 0, stream>>>(fw0, fw1, fw2, ww0, ww1, ww2, wsf);
  green_kernel<<<16 * 64 * 9, 256, 0, stream>>>(mosaic, wsf, green, out);
  assemble_kernel<<<(16 * HH * WW) / 256, 256, 0, stream>>>(mosaic, green, cw0, out);
}

// Round 15
// 191.045 us; speedup vs baseline: 1.2031x; 1.0074x over previous
//
#include <hip/hip_runtime.h>
#include <cstdint>

#define HH 512
#define WW 512
#define TX 58          // output tile width; 9 tiles cover 512 (last partial)
// grid = 16 * 64 * 9 = 9216 blocks

typedef __attribute__((ext_vector_type(8)))  short    short8;
typedef __attribute__((ext_vector_type(16))) float    f32x16;
typedef __attribute__((ext_vector_type(4)))  float    f32x4;
typedef __attribute__((ext_vector_type(2)))  unsigned u32x2;
typedef __attribute__((ext_vector_type(8)))  int      int8v;

union FragU { uint4 u; short8 s; };
union B8U   { u32x2 u2[2]; short8 s; };
union AF8   { uint4 u[2]; int8v v; };
union BF8   { unsigned d[8]; int8v v; };

// 8-byte, 4-aligned pair load -> single ds_read2_b32 / unaligned b64 (halves LDS issue)
struct U2 { unsigned x, y; };

// ---- LDS layout (bytes); fp8 act slot = 12B; row stride 832B (208dw==16 mod 32,
// conflict-minimal per R12) ----
#define L1F_O  0        // 12 rows x 832B (62 px = 744B used, tail zeroed)
#define L1W_O  9984
#define L1RST  832
#define MOS_O  19968    // 14 rows x 64 px x 8B bf16 (dead after L1)
#define MOSR   512
#define L2F_O  19968    // aliases mosaic; 10 rows x 832B (60 px = 720B used, tail zeroed)
#define L2W_O  28288
#define L2RST  832
#define RELAY_O 0       // aliases dead L1 during L3; 4 waves x 64 slots x 52B = 13312
#define SMEMB  36608    // 4 blocks/CU

#define MFMA_SC(A, B, C) \
  __builtin_amdgcn_mfma_scale_f32_16x16x128_f8f6f4((A), (B), (C), 0, 0, 0, 0x7F7F7F7Fu, 0, 0x7F7F7F7Fu)

__device__ __forceinline__ unsigned cvtpk(float a, float b) {
  unsigned r;
  asm("v_cvt_pk_bf16_f32 %0, %1, %2" : "=v"(r) : "v"(a), "v"(b));
  return r;
}
__device__ __forceinline__ unsigned rpk8(float a, float b, float c, float d, bool im) {
  int r = __builtin_amdgcn_cvt_pk_fp8_f32(fmaxf(a, 0.f), fmaxf(b, 0.f), 0, false);
  r = __builtin_amdgcn_cvt_pk_fp8_f32(fmaxf(c, 0.f), fmaxf(d, 0.f), r, true);
  return im ? (unsigned)r : 0u;
}
__device__ __forceinline__ unsigned short f2bf(float f) {
  union { float f; unsigned u; } v; v.f = f;
  unsigned r = v.u + 0x7fffu + ((v.u >> 16) & 1u);
  return (unsigned short)(r >> 16);
}
__device__ __forceinline__ float lo16(unsigned u) {
  union { unsigned v; float f; } x; x.v = u << 16; return x.f;
}
__device__ __forceinline__ float hi16(unsigned u) {
  union { unsigned v; float f; } x; x.v = u & 0xffff0000u; return x.f;
}

// ---------------- weight packer (EXACT R10/R12 mapping — HW-verified) ----------------
// t 0-191: L1 merged bf16 frags (f=t>>6=ky), rows 0-11 fw0, 12-23 ww0;
//          slot sq = 2h + e/4 -> kx = sq (sq==3 zero). 16B/lane.
// t 192-447: scaled K=128 frags, sid={L2F,L2W,L3F,L3W} at 192+sid*128+lane*2.
//   lane: m=lane&15 (co), kg=lane>>4.
//   kg<3 : byte e (0-31): dx=e/12, ci=e%12, tap=kg*3+dx.
//   kg==3: e=8i+j, valid i<3,j<4: tap=i*3+2, ci=8+j (row-tails); else 0.
// L3 W set pre-scaled 1/ln2 (softmax via exp2).
__global__ void wt_kernel(const float* __restrict__ fw0, const float* __restrict__ fw1,
                          const float* __restrict__ fw2, const float* __restrict__ ww0,
                          const float* __restrict__ ww1, const float* __restrict__ ww2,
                          uint4* __restrict__ wsf) {
  int t = blockIdx.x * 256 + threadIdx.x;
  if (t >= 448) return;
  if (t < 192) {
    int f = t >> 6, lane = t & 63;
    int h = (lane >> 5) & 1, m = lane & 31;
    unsigned short v[8];
#pragma unroll
    for (int e = 0; e < 8; ++e) {
      int sq = 2 * h + (e >> 2);
      int c4 = e & 3;
      float w = 0.f;
      if (sq < 3 && m < 24) {
        w = (m < 12) ? fw0[(m * 4 + c4) * 9 + f * 3 + sq]
                     : ww0[((m - 12) * 4 + c4) * 9 + f * 3 + sq];
      }
      v[e] = f2bf(w);
    }
    uint4 o;
    o.x = (unsigned)v[0] | ((unsigned)v[1] << 16);
    o.y = (unsigned)v[2] | ((unsigned)v[3] << 16);
    o.z = (unsigned)v[4] | ((unsigned)v[5] << 16);
    o.w = (unsigned)v[6] | ((unsigned)v[7] << 16);
    wsf[t] = o;
  } else {
    int u = t - 192, sid = u >> 6, lane = u & 63;
    int m = lane & 15, kg = lane >> 4;
    int layer = sid >> 1, path = sid & 1;
    const float* src = layer ? (path ? ww2 : fw2) : (path ? ww1 : fw1);
    const float scale = (layer == 1 && path == 1) ? 1.44269504f : 1.0f;
    unsigned d[8];
#pragma unroll
    for (int k = 0; k < 8; ++k) {
      float w4[4];
#pragma unroll
      for (int j4 = 0; j4 < 4; ++j4) {
        int e = 4 * k + j4;
        float w = 0.f;
        if (m < 12) {
          if (kg < 3) {
            int dx = e / 12, ci = e % 12, tap = kg * 3 + dx;
            w = src[(m * 12 + ci) * 9 + tap] * scale;
          } else {
            int i = e >> 3, j = e & 7;
            if (i < 3 && j < 4) {
              int tap = i * 3 + 2, ci = 8 + j;
              w = src[(m * 12 + ci) * 9 + tap] * scale;
            }
          }
        }
        w4[j4] = w;
      }
      int x = __builtin_amdgcn_cvt_pk_fp8_f32(w4[0], w4[1], 0, false);
      x = __builtin_amdgcn_cvt_pk_fp8_f32(w4[2], w4[3], x, true);
      d[k] = (unsigned)x;
    }
    uint4* dst = wsf + 192 + sid * 128 + lane * 2;
    dst[0] = make_uint4(d[0], d[1], d[2], d[3]);
    dst[1] = make_uint4(d[4], d[5], d[6], d[7]);
  }
}

// ---------------- fused 3-layer x 2-path conv (MX K=128 MFMA) + softmax green ----------------
// Writes G output plane + interleaved green u32 buffer.
__global__ __launch_bounds__(256, 4)
void green_kernel(const float* __restrict__ mosaic, const uint4* __restrict__ wsf,
                  unsigned* __restrict__ green, float* __restrict__ out) {
  __shared__ __align__(16) char s[SMEMB];
  const int tid = threadIdx.x;
  const int lane = tid & 63;
  const int wv = __builtin_amdgcn_readfirstlane(tid >> 6);
  const int h = (lane >> 5) & 1, ln = lane & 31;
  const int ln8 = ln * 8, ln12 = ln * 12;
  const int pxl = lane & 15, kg = lane >> 4;
  const int bid = blockIdx.x;
  const int bx = bid % 9;
  const int t9 = bid / 9;
  const int by = t9 & 63, b = t9 >> 6;
  const int X0 = bx * TX, Y0 = by * 8;
  const float* __restrict__ mb = mosaic + (size_t)b * 4 * HH * WW;

  // ---- stage 0: mosaic tile 14x64 bf16 + zero L1 row tails (pad-read safety) ----
  {
    for (int p = tid; p < 14 * 64; p += 256) {
      int row = p >> 6, col = p & 63;
      int gy = Y0 + row - 3, gx = X0 + col - 3;
      float c0 = 0.f, c1 = 0.f, c2 = 0.f, c3 = 0.f;
      if ((unsigned)gy < HH && (unsigned)gx < WW) {
        const float* mp = mb + (size_t)gy * WW + gx;
        c0 = mp[0]; c1 = mp[HH * WW]; c2 = mp[2 * HH * WW]; c3 = mp[3 * HH * WW];
      }
      u32x2 w = { cvtpk(c0, c1), cvtpk(c2, c3) };
      *(u32x2*)(s + MOS_O + row * MOSR + col * 8) = w;
    }
    for (int i = tid; i < 528; i += 256) {   // 24 segs x 22 dw: L1F/L1W tails 744..832
      int seg = i / 22, d = i - seg * 22;
      int row = seg % 12, w = seg / 12;
      *(unsigned*)(s + w * 9984 + row * 832 + 744 + d * 4) = 0u;
    }
  }
  __syncthreads();

  // ---- L1: 4->12 both paths in one bf16 MFMA (M: F 0-11, W 12-23), out 12x62 fp8 ----
  {
    FragU a3[3];
#pragma unroll
    for (int q = 0; q < 3; ++q) a3[q].u = wsf[q * 64 + lane];
    const char* pLo = s + MOS_O + 3 * wv * MOSR + ln8 + 16 * h;
    const char* pHi = s + MOS_O + 3 * wv * MOSR + ln8 + 8;
    char* base = s + 3 * wv * L1RST + ln12;
    char* pA = base + L1F_O + 4 * h;
    char* pB = h ? base + L1W_O : base + L1F_O + 8;
    char* pC = base + L1W_O + (h ? 8 : 4);
    bool ck[2];
    ck[0] = (unsigned)(X0 + 0  + ln - 2) < WW;
    ck[1] = (unsigned)(X0 + 30 + ln - 2) < WW;
#pragma unroll
    for (int r = 0; r < 3; ++r) {
      const int ly = 3 * wv + r;
      const bool rowok = (unsigned)(Y0 + ly - 2) < HH;
#pragma unroll
      for (int g = 0; g < 2; ++g) {
        const int cb = g * 30;
        f32x16 c = {};
#pragma unroll
        for (int ky = 0; ky < 3; ++ky) {
          B8U bu;
          bu.u2[0] = *(const u32x2*)(pLo + (r + ky) * MOSR + cb * 8);
          bu.u2[1] = *(const u32x2*)(pHi + (r + ky) * MOSR + cb * 8);
          c = __builtin_amdgcn_mfma_f32_32x32x16_bf16(a3[ky].s, bu.s, c, 0, 0, 0);
        }
        const bool im = rowok && ck[g];
        *(unsigned*)(pA + r * L1RST + cb * 12) = rpk8(c[0], c[1], c[2], c[3], im);
        *(unsigned*)(pB + r * L1RST + cb * 12) = rpk8(c[4], c[5], c[6], c[7], im);
        *(unsigned*)(pC + r * L1RST + cb * 12) = rpk8(c[8], c[9], c[10], c[11], im);
      }
    }
  }
  __syncthreads();

  // ---- L2: 12->12 both chains, ONE scaled MFMA per 16px per chain, out 10x60 ----
  {
    // zero L2F/L2W row tails 720..832 (mosaic now dead; visible to L3 via next barrier)
    for (int i = tid; i < 560; i += 256) {   // 20 segs x 28 dw
      int seg = i / 28, d = i - seg * 28;
      int row = seg % 10, w = seg / 10;
      *(unsigned*)(s + L2F_O + w * 8320 + row * 832 + 720 + d * 4) = 0u;
    }
    AF8 aF, aW;
    aF.u[0] = wsf[192 + lane * 2]; aF.u[1] = wsf[193 + lane * 2];
    aW.u[0] = wsf[320 + lane * 2]; aW.u[1] = wsf[321 + lane * 2];
    const int c0 = (wv == 0) ? 0 : (wv == 1) ? 16 : (wv == 2) ? 32 : 44;
    int o0, o1, o2, o3;
    if (kg < 3) { o0 = kg * L1RST + pxl * 12; o1 = o0 + 8; o2 = o0 + 16; o3 = o0 + 24; }
    else        { o0 = (pxl + 2) * 12 + 8; o1 = o0 + L1RST; o2 = o1 + L1RST; o3 = o2; }
    const char* P0 = s + L1F_O + c0 * 12 + o0;
    const char* P1 = s + L1F_O + c0 * 12 + o1;
    const char* P2 = s + L1F_O + c0 * 12 + o2;
    const char* P3 = s + L1F_O + c0 * 12 + o3;
    const bool ckx = (unsigned)(X0 + c0 + pxl - 1) < WW;
    char* pO = s + L2F_O + (c0 + pxl) * 12 + 4 * kg;
#pragma unroll
    for (int ly = 0; ly < 10; ++ly) {
      const int imm = ly * L1RST;
      U2 f0 = *(const U2*)(P0 + imm);
      U2 f1 = *(const U2*)(P1 + imm);
      U2 f2 = *(const U2*)(P2 + imm);
      U2 f3 = *(const U2*)(P3 + imm);
      U2 w0 = *(const U2*)(P0 + imm + 9984);
      U2 w1 = *(const U2*)(P1 + imm + 9984);
      U2 w2 = *(const U2*)(P2 + imm + 9984);
      U2 w3 = *(const U2*)(P3 + imm + 9984);
      BF8 bF, bW;
      bF.d[0] = f0.x; bF.d[1] = f0.y; bF.d[2] = f1.x; bF.d[3] = f1.y;
      bF.d[4] = f2.x; bF.d[5] = f2.y; bF.d[6] = f3.x; bF.d[7] = f3.y;
      bW.d[0] = w0.x; bW.d[1] = w0.y; bW.d[2] = w1.x; bW.d[3] = w1.y;
      bW.d[4] = w2.x; bW.d[5] = w2.y; bW.d[6] = w3.x; bW.d[7] = w3.y;
      f32x4 cF = {0.f, 0.f, 0.f, 0.f}, cW = {0.f, 0.f, 0.f, 0.f};
      cF = MFMA_SC(aF.v, bF.v, cF);
      cW = MFMA_SC(aW.v, bW.v, cW);
      const bool im = ckx && ((unsigned)(Y0 + ly - 1) < HH);
      if (kg < 3) {
        *(unsigned*)(pO + ly * L2RST)        = rpk8(cF[0], cF[1], cF[2], cF[3], im);
        *(unsigned*)(pO + ly * L2RST + 8320) = rpk8(cW[0], cW[1], cW[2], cW[3], im);
      }
    }
  }
  __syncthreads();

  // ---- L3: scaled MFMA + relay (52B slots) + softmax -> green + G-plane, out 8x58 ----
  {
    AF8 aF, aW;
    aF.u[0] = wsf[448 + lane * 2]; aF.u[1] = wsf[449 + lane * 2];
    aW.u[0] = wsf[576 + lane * 2]; aW.u[1] = wsf[577 + lane * 2];
    const int c0 = (wv == 0) ? 0 : (wv == 1) ? 16 : (wv == 2) ? 32 : 42;
    int o0, o1, o2, o3;
    if (kg < 3) { o0 = kg * L2RST + pxl * 12; o1 = o0 + 8; o2 = o0 + 16; o3 = o0 + 24; }
    else        { o0 = (pxl + 2) * 12 + 8; o1 = o0 + L2RST; o2 = o1 + L2RST; o3 = o2; }
    const char* P0 = s + L2F_O + c0 * 12 + o0;
    const char* P1 = s + L2F_O + c0 * 12 + o1;
    const char* P2 = s + L2F_O + c0 * 12 + o2;
    const char* P3 = s + L2F_O + c0 * 12 + o3;
    char* relay = s + RELAY_O + wv * 3328;
#pragma unroll
    for (int half = 0; half < 2; ++half) {
#pragma unroll
      for (int rr = 0; rr < 4; ++rr) {
        const int imm = (half * 4 + rr) * L2RST;
        U2 f0 = *(const U2*)(P0 + imm);
        U2 f1 = *(const U2*)(P1 + imm);
        U2 f2 = *(const U2*)(P2 + imm);
        U2 f3 = *(const U2*)(P3 + imm);
        U2 w0 = *(const U2*)(P0 + imm + 8320);
        U2 w1 = *(const U2*)(P1 + imm + 8320);
        U2 w2 = *(const U2*)(P2 + imm + 8320);
        U2 w3 = *(const U2*)(P3 + imm + 8320);
        BF8 bF, bW;
        bF.d[0] = f0.x; bF.d[1] = f0.y; bF.d[2] = f1.x; bF.d[3] = f1.y;
        bF.d[4] = f2.x; bF.d[5] = f2.y; bF.d[6] = f3.x; bF.d[7] = f3.y;
        bW.d[0] = w0.x; bW.d[1] = w0.y; bW.d[2] = w1.x; bW.d[3] = w1.y;
        bW.d[4] = w2.x; bW.d[5] = w2.y; bW.d[6] = w3.x; bW.d[7] = w3.y;
        f32x4 cF = {0.f, 0.f, 0.f, 0.f}, cW = {0.f, 0.f, 0.f, 0.f};
        cF = MFMA_SC(aF.v, bF.v, cF);
        cW = MFMA_SC(aW.v, bW.v, cW);
        if (kg < 3) {
          char* slot = relay + ((rr << 4) + pxl) * 52 + kg * 8;
          *(unsigned*)(slot)      = cvtpk(fmaxf(cF[0], 0.f), fmaxf(cF[1], 0.f));
          *(unsigned*)(slot + 4)  = cvtpk(fmaxf(cF[2], 0.f), fmaxf(cF[3], 0.f));
          *(unsigned*)(slot + 24) = cvtpk(fmaxf(cW[0], 0.f), fmaxf(cW[1], 0.f));
          *(unsigned*)(slot + 28) = cvtpk(fmaxf(cW[2], 0.f), fmaxf(cW[3], 0.f));
        }
      }
      asm volatile("s_waitcnt lgkmcnt(0)" ::: "memory");
      {
        const char* slot = relay + lane * 52;
        unsigned fu[6], wu[6];
#pragma unroll
        for (int i = 0; i < 3; ++i) {
          U2 a = *(const U2*)(slot + i * 8);
          U2 c = *(const U2*)(slot + 24 + i * 8);
          fu[2 * i] = a.x; fu[2 * i + 1] = a.y;
          wu[2 * i] = c.x; wu[2 * i + 1] = c.y;
        }
        float F[12], Wv[12];
#pragma unroll
        for (int i = 0; i < 6; ++i) {
          F[2 * i] = lo16(fu[i]);  F[2 * i + 1] = hi16(fu[i]);
          Wv[2 * i] = lo16(wu[i]); Wv[2 * i + 1] = hi16(wu[i]);
        }
        float m = 0.f;
#pragma unroll
        for (int c2 = 0; c2 < 12; ++c2) m = fmaxf(m, Wv[c2]);
        float sum = 0.f, s0 = 0.f, s1 = 0.f;
#pragma unroll
        for (int c2 = 0; c2 < 12; ++c2) {
          const float e = exp2f(Wv[c2] - m);   // W logits pre-scaled by 1/ln2
          sum += e;
          if (c2 < 6) s0 = fmaf(F[c2], e, s0);
          else        s1 = fmaf(F[c2], e, s1);
        }
        const float inv = 1.f / sum;
        const float g0s = s0 * inv, g1s = s1 * inv;
        const unsigned pg = cvtpk(g0s, g1s);
        const int gy = Y0 + half * 4 + kg;
        const int gx = X0 + c0 + pxl;
        if ((unsigned)gx < WW) {
          green[((size_t)b * HH + gy) * WW + gx] = pg;
          // G output plane: tl=m0 tr=g0 / bl=g1 br=m3 (center-only, fp32 green)
          const int p = gy * WW + gx;
          const float m0 = mb[p];
          const float m3 = mb[3 * HH * WW + p];
          const int W2 = 2 * WW;
          size_t gbase = (((size_t)(b * 3 + 1)) * (2 * HH) + 2 * gy) * (size_t)W2 + 2 * gx;
          *(float2*)(out + gbase)      = make_float2(m0, g0s);
          *(float2*)(out + gbase + W2) = make_float2(g1s, m3);
        }
      }
      asm volatile("s_waitcnt lgkmcnt(0)" ::: "memory");
    }
  }
}

// ---------------- chroma conv 2->6 + pixel-shuffle assembly (R and B planes only) ----------------
__global__ __launch_bounds__(256)
void assemble_kernel(const float* __restrict__ mosaic, const unsigned* __restrict__ green,
                     const float* __restrict__ cw0, float* __restrict__ out) {
  const int t = blockIdx.x * 256 + threadIdx.x;
  const int x = t & (WW - 1);
  const int y = (t >> 9) & (HH - 1);
  const int b = t >> 18;

  const int p = y * WW + x;
  const float* __restrict__ mb = mosaic + (size_t)b * 4 * HH * WW;
  const unsigned* __restrict__ gb = green + (size_t)b * HH * WW;

  const float m0 = mb[p];
  const float m1 = mb[HH * WW + p];
  const float m2 = mb[2 * HH * WW + p];
  const float m3 = mb[3 * HH * WW + p];
  const unsigned gc = gb[p];
  const float g0 = lo16(gc);
  const float g1 = hi16(gc);

  float cd[6] = {0.f, 0.f, 0.f, 0.f, 0.f, 0.f};
#pragma unroll
  for (int ky = 0; ky < 3; ++ky) {
#pragma unroll
    for (int kx = 0; kx < 3; ++kx) {
      const int yy = y + ky - 1, xx = x + kx - 1;
      float c0 = 0.f, c1 = 0.f;
      if ((unsigned)yy < HH && (unsigned)xx < WW) {
        const int q = yy * WW + xx;
        const unsigned gg = gb[q];
        c0 = mb[HH * WW + q]     - lo16(gg);
        c1 = mb[2 * HH * WW + q] - hi16(gg);
      }
      const int k = ky * 3 + kx;
#pragma unroll
      for (int o = 0; o < 6; ++o) {
        cd[o] = fmaf(c0, cw0[(o * 2 + 0) * 9 + k], cd[o]);
        cd[o] = fmaf(c1, cw0[(o * 2 + 1) * 9 + k], cd[o]);
      }
    }
  }
  const float cp0 = cd[0] + m0;
  const float cp1 = cd[1] + g1;
  const float cp2 = cd[2] + m3;
  const float cp3 = cd[3] + m0;
  const float cp4 = cd[4] + g0;
  const float cp5 = cd[5] + m3;

  const int W2 = 2 * WW;
  const size_t plane = (size_t)(2 * HH) * W2;
  size_t base = ((size_t)(b * 3) * (2 * HH) + 2 * y) * W2 + 2 * x;
  // R: tl=cp0 tr=m1 / bl=cp1 br=cp2
  *(float2*)(out + base)          = make_float2(cp0, m1);
  *(float2*)(out + base + W2)     = make_float2(cp1, cp2);
  // (G plane written by green_kernel)
  // B: tl=cp3 tr=cp4 / bl=m2 br=cp5
  *(float2*)(out + base + 2 * plane)      = make_float2(cp3, cp4);
  *(float2*)(out + base + 2 * plane + W2) = make_float2(m2, cp5);
}

extern "C" void kernel_launch(void* const* d_in, const int* in_sizes, int n_in,
                              void* d_out, int out_size, void* d_ws, size_t ws_size,
                              hipStream_t stream) {
  const float* mosaic = (const float*)d_in[0];
  const float* fw0 = (const float*)d_in[1];
  const float* fw1 = (const float*)d_in[2];
  const float* fw2 = (const float*)d_in[3];
  const float* ww0 = (const float*)d_in[4];
  const float* ww1 = (const float*)d_in[5];
  const float* ww2 = (const float*)d_in[6];
  const float* cw0 = (const float*)d_in[7];

  uint4* wsf = (uint4*)((char*)d_ws + 32768);
  unsigned* green = (unsigned*)((char*)d_ws + 67584);
  float* out = (float*)d_out;

  wt_kernel<<<2, 256, 0, stream>>>(fw0, fw1, fw2, ww0, ww1, ww2, wsf);
  green_kernel<<<16 * 64 * 9, 256, 0, stream>>>(mosaic, wsf, green, out);
  assemble_kernel<<<(16 * HH * WW) / 256, 256, 0, stream>>>(mosaic, green, cw0, out);
}